// Round 4
// baseline (316.559 us; speedup 1.0000x reference)
//
#include <hip/hip_runtime.h>

#define BB    8
#define LQN   2048
#define LKVN  2048
#define DQ    128
#define DVN   128
#define QT    16      // Q rows per block
#define KT    64      // phase-2 KV tile
#define NT    (LKVN / KT)    // 32
#define PSTR  72      // pl row stride (bf16)
#define WSTR  68      // pw row stride (fp32)

typedef short short8 __attribute__((ext_vector_type(8)));
typedef float f32x4  __attribute__((ext_vector_type(4)));

// LDS-only barrier: does NOT drain global stores/loads (vmcnt untouched).
#define BAR() asm volatile("s_waitcnt lgkmcnt(0)\n\ts_barrier" ::: "memory")

__device__ __forceinline__ short f2bf(float f) {
  unsigned u = __builtin_bit_cast(unsigned, f);
  u += 0x7fffu + ((u >> 16) & 1u);   // round-to-nearest-even
  return (short)(u >> 16);
}

// Q,K fp32 -> bf16 row-major
__global__ __launch_bounds__(256) void conv_kernel(const float* __restrict__ Q,
                                                   const float* __restrict__ K,
                                                   short* __restrict__ Qb,
                                                   short* __restrict__ Kb) {
  int i = blockIdx.x * 256 + threadIdx.x;
  const float* s; short* d;
  if (i < 262144) { s = Q; d = Qb; }
  else            { s = K; d = Kb; i -= 262144; }
  size_t off = (size_t)i * 8;
  float4 a = *(const float4*)(s + off);
  float4 b = *(const float4*)(s + off + 4);
  short8 o;
  o[0] = f2bf(a.x); o[1] = f2bf(a.y); o[2] = f2bf(a.z); o[3] = f2bf(a.w);
  o[4] = f2bf(b.x); o[5] = f2bf(b.y); o[6] = f2bf(b.z); o[7] = f2bf(b.w);
  *(short8*)(d + off) = o;
}

// V (B, LKV, DV) fp32 -> Vt (B, DV, LKV) bf16
__global__ __launch_bounds__(256) void vtrans_kernel(const float* __restrict__ V,
                                                     short* __restrict__ Vt) {
  __shared__ float tile[128][33];
  const int kv0 = blockIdx.x * 128;
  const int dv0 = blockIdx.y * 32;
  const int b   = blockIdx.z;
  const int tid = threadIdx.x;
  const float* src = V + ((size_t)b * LKVN + kv0) * DVN + dv0;
#pragma unroll
  for (int it = 0; it < 4; ++it) {
    int idx = it * 256 + tid;
    int r = idx >> 3, c4 = idx & 7;
    float4 v = *(const float4*)(src + (size_t)r * DVN + c4 * 4);
    tile[r][c4 * 4 + 0] = v.x;
    tile[r][c4 * 4 + 1] = v.y;
    tile[r][c4 * 4 + 2] = v.z;
    tile[r][c4 * 4 + 3] = v.w;
  }
  __syncthreads();
  short* dst = Vt + ((size_t)b * DVN + dv0) * LKVN + kv0;
#pragma unroll
  for (int it = 0; it < 2; ++it) {
    int idx = it * 256 + tid;
    int row = idx >> 4, ch = idx & 15;
    short8 o;
#pragma unroll
    for (int j = 0; j < 8; ++j) o[j] = f2bf(tile[ch * 8 + j][row]);
    *(short8*)(dst + (size_t)row * LKVN + ch * 8) = o;
  }
}

// Block = 16 Q rows of one batch, 4 waves. All K/V frag reads DIRECT from
// global (L2-resident, XCD-pinned). LDS only for the p bounce (bf16 A-frags),
// the fp32 W-writeback tile (guarantees full-line coalesced W stores), and
// the l reduction. Phase 1 barrier-free; phase 2 one lgkm-barrier per tile.
__global__ __launch_bounds__(256, 4) void attn_kernel(const short* __restrict__ Qb,
                                                      const short* __restrict__ Kb,
                                                      const short* __restrict__ Vt,
                                                      float* __restrict__ W,
                                                      float* __restrict__ O) {
  __shared__ __align__(16) short pl[2][QT][PSTR];   // bf16 P (A-frag bounce)
  __shared__ __align__(16) float pw[2][QT][WSTR];   // fp32 P (W writeback)
  __shared__ float redl[4][QT];
  __shared__ float statr[QT];

  const int tid  = threadIdx.x;
  const int w    = tid >> 6;
  const int lane = tid & 63;
  const int n    = lane & 15;
  const int qd   = lane >> 4;
  const int b    = blockIdx.x & 7;          // batch -> XCD-pinned L2 locality
  const int q0   = (blockIdx.x >> 3) * QT;

  const short* Kbase = Kb + (size_t)b * LKVN * DQ;
  const short* Vbase = Vt + (size_t)b * DVN * LKVN;

  // Q A-frags (registers, both phases): A[m=n][k=qd*8+j + ks*32]
  short8 qf[4];
  {
    const short* Qrow = Qb + ((size_t)b * LQN + q0 + n) * DQ + qd * 8;
#pragma unroll
    for (int ks = 0; ks < 4; ++ks) qf[ks] = *(const short8*)(Qrow + ks * 32);
  }

  const float k2c = (float)(0.08838834764831845 * 1.4426950408889634); // scale*log2e
  float l_part[4] = {0.f, 0.f, 0.f, 0.f};

  // ---------------- phase 1: l = row sums of exp(s), barrier-free ----------------
  // wave w sweeps col-tiles [w*32, w*32+32): B-frag lane (n,qd) reads K row ct*16+n.
  {
    const short* Kp = Kbase + ((size_t)(w * 32 * 16 + n)) * DQ + qd * 8;
    short8 kb[2][4];
#pragma unroll
    for (int ks = 0; ks < 4; ++ks) kb[0][ks] = *(const short8*)(Kp + ks * 32);
#pragma unroll 2
    for (int i = 0; i < 32; ++i) {
      const int cur = i & 1, nxt = cur ^ 1;
      if (i + 1 < 32) {
        const short* src = Kp + (size_t)(i + 1) * 16 * DQ;
#pragma unroll
        for (int ks = 0; ks < 4; ++ks) kb[nxt][ks] = *(const short8*)(src + ks * 32);
      }
      f32x4 acc = {0.f, 0.f, 0.f, 0.f};
#pragma unroll
      for (int ks = 0; ks < 4; ++ks)
        acc = __builtin_amdgcn_mfma_f32_16x16x32_bf16(qf[ks], kb[cur][ks], acc, 0, 0, 0);
#pragma unroll
      for (int r = 0; r < 4; ++r) l_part[r] += exp2f(acc[r] * k2c);
    }
  }

  // reduce l across 16 n-lanes, then across waves
#pragma unroll
  for (int r = 0; r < 4; ++r)
#pragma unroll
    for (int off = 1; off < 16; off <<= 1)
      l_part[r] += __shfl_xor(l_part[r], off, 64);
  if (n == 0)
#pragma unroll
    for (int r = 0; r < 4; ++r) redl[w][qd * 4 + r] = l_part[r];
  __syncthreads();
  if (tid < QT)
    statr[tid] = 1.0f / (redl[0][tid] + redl[1][tid] + redl[2][tid] + redl[3][tid]);
  __syncthreads();
  float rinv[4];
#pragma unroll
  for (int r = 0; r < 4; ++r) rinv[r] = statr[qd * 4 + r];

  // ---------------- phase 2: W = P + O = P V ----------------
  f32x4 oacc[2];
  oacc[0] = (f32x4){0.f, 0.f, 0.f, 0.f};
  oacc[1] = (f32x4){0.f, 0.f, 0.f, 0.f};
  float* Wb = W + ((size_t)b * LQN + q0) * LKVN;

  // phase-2 direct-global frag bases
  const short* Kp2 = Kbase + ((size_t)(w * 16 + n)) * DQ + qd * 8;          // S-tile rows
  const short* Vp2 = Vbase + ((size_t)(w * 32 + n)) * LKVN + qd * 8;        // dv rows w*32+c*16+n
  const int wrow = tid >> 4, wcol = (tid & 15) * 4;                          // W coop store map

  short8 kfb[2][4], vfb[2][4];
#pragma unroll
  for (int ks = 0; ks < 4; ++ks) kfb[0][ks] = *(const short8*)(Kp2 + ks * 32);
#pragma unroll
  for (int c = 0; c < 2; ++c) {
    vfb[0][c * 2 + 0] = *(const short8*)(Vp2 + (size_t)c * 16 * LKVN);
    vfb[0][c * 2 + 1] = *(const short8*)(Vp2 + (size_t)c * 16 * LKVN + 32);
  }

#pragma unroll 2
  for (int t = 0; t < NT; ++t) {
    const int kv0 = t * KT;
    const int cur = t & 1, nxt = cur ^ 1;
    if (t + 1 < NT) {
      const short* ks2 = Kp2 + (size_t)(kv0 + KT) * DQ;
      const short* vs2 = Vp2 + kv0 + KT;
#pragma unroll
      for (int ks = 0; ks < 4; ++ks) kfb[nxt][ks] = *(const short8*)(ks2 + ks * 32);
#pragma unroll
      for (int c = 0; c < 2; ++c) {
        vfb[nxt][c * 2 + 0] = *(const short8*)(vs2 + (size_t)c * 16 * LKVN);
        vfb[nxt][c * 2 + 1] = *(const short8*)(vs2 + (size_t)c * 16 * LKVN + 32);
      }
    }
    f32x4 acc = {0.f, 0.f, 0.f, 0.f};
#pragma unroll
    for (int ks = 0; ks < 4; ++ks)
      acc = __builtin_amdgcn_mfma_f32_16x16x32_bf16(qf[ks], kfb[cur][ks], acc, 0, 0, 0);
    float p[4];
#pragma unroll
    for (int r = 0; r < 4; ++r) p[r] = exp2f(acc[r] * k2c) * rinv[r];
#pragma unroll
    for (int r = 0; r < 4; ++r) {
      pw[cur][qd * 4 + r][w * 16 + n] = p[r];          // fp32 for W writeback
      pl[cur][qd * 4 + r][w * 16 + n] = f2bf(p[r]);    // bf16 for PV A-frag
    }
    BAR();                                             // p visible block-wide
    // cooperative, guaranteed full-line W store: wave = 4 rows x 256 B
    {
      float4 wv = *(const float4*)&pw[cur][wrow][wcol];
      *(float4*)(Wb + (size_t)wrow * LKVN + kv0 + wcol) = wv;  // fire-and-forget
    }
    short8 pa0 = *(const short8*)&pl[cur][n][qd * 8];
    short8 pa1 = *(const short8*)&pl[cur][n][32 + qd * 8];
    oacc[0] = __builtin_amdgcn_mfma_f32_16x16x32_bf16(pa0, vfb[cur][0], oacc[0], 0, 0, 0);
    oacc[0] = __builtin_amdgcn_mfma_f32_16x16x32_bf16(pa1, vfb[cur][1], oacc[0], 0, 0, 0);
    oacc[1] = __builtin_amdgcn_mfma_f32_16x16x32_bf16(pa0, vfb[cur][2], oacc[1], 0, 0, 0);
    oacc[1] = __builtin_amdgcn_mfma_f32_16x16x32_bf16(pa1, vfb[cur][3], oacc[1], 0, 0, 0);
  }

  float* Ob = O + ((size_t)b * LQN + q0) * DVN;
#pragma unroll
  for (int c = 0; c < 2; ++c)
#pragma unroll
    for (int r = 0; r < 4; ++r)
      Ob[(size_t)(qd * 4 + r) * DVN + w * 32 + c * 16 + n] = oacc[c][r];
}

extern "C" void kernel_launch(void* const* d_in, const int* in_sizes, int n_in,
                              void* d_out, int out_size, void* d_ws, size_t ws_size,
                              hipStream_t stream) {
  const float* Q = (const float*)d_in[0];
  const float* K = (const float*)d_in[1];
  const float* V = (const float*)d_in[2];
  float* W = (float*)d_out;                        // (B, LQ, LKV)
  float* O = W + (size_t)BB * LQN * LKVN;          // (B, LQ, DV)
  short* Qb = (short*)d_ws;
  short* Kb = Qb + (size_t)BB * LQN * DQ;
  short* Vt = Kb + (size_t)BB * LKVN * DQ;

  conv_kernel<<<2048, 256, 0, stream>>>(Q, K, Qb, Kb);
  vtrans_kernel<<<dim3(LKVN / 128, DVN / 32, BB), 256, 0, stream>>>(V, Vt);
  attn_kernel<<<1024, 256, 0, stream>>>(Qb, Kb, Vt, W, O);
}